// Round 1
// baseline (101.438 us; speedup 1.0000x reference)
//
#include <hip/hip_runtime.h>

#define NN 4096
#define MM 8191   // 2*NN - 1
#define BB 256

// ---------------------------------------------------------------------------
// Kernel 1: dd = d1 - d2 (into workspace), and zero the 256-float w1 accum.
// ---------------------------------------------------------------------------
__global__ __launch_bounds__(256) void k_diff_zero(const float* __restrict__ d1,
                                                   const float* __restrict__ d2,
                                                   float* __restrict__ ws,
                                                   int make_dd) {
    int idx = blockIdx.x * 256 + threadIdx.x;
    if (idx < BB) ws[idx] = 0.0f;           // w1sum accumulator at ws[0..255]
    if (make_dd) {
        float* dd = ws + BB;
        int stride = gridDim.x * 256;
        for (int i = idx; i < NN * BB; i += stride) dd[i] = d1[i] - d2[i];
    }
}

// ---------------------------------------------------------------------------
// Kernel 2: for each tree node m (grid-stride over rows):
//   scan subtree[m, :] (134 MB total stream, the HBM-bound part),
//   push nonzero column indices into an LDS list,
//   thread b accumulates acc = sum dd[n, b] over the list (L2-hot gathers),
//   partial[b] += (param[parents[m]] - param[m]) * |acc|.
// One global atomicAdd per (block, b) at the end.
// ---------------------------------------------------------------------------
__global__ __launch_bounds__(256, 4) void k_tree_w1(
        const float* __restrict__ subtree,
        const float* __restrict__ d1,
        const float* __restrict__ d2,
        const float* __restrict__ dd,
        int use_dd,
        const float* __restrict__ param,
        const int*   __restrict__ parents,
        float* __restrict__ w1sum) {
    __shared__ int s_idx[NN];   // worst case: all columns nonzero (16 KB)
    __shared__ int s_cnt;
    const int tid = threadIdx.x;
    float partial = 0.0f;

    for (int m = blockIdx.x; m < MM; m += gridDim.x) {
        if (tid == 0) s_cnt = 0;
        __syncthreads();

        // --- scan: 4096 floats = 1024 float4; 256 threads x 4 each, coalesced
        const float4* row = (const float4*)(subtree + (size_t)m * NN);
        #pragma unroll
        for (int k = 0; k < 4; ++k) {
            int j = tid + k * 256;
            float4 v = row[j];
            int base = j * 4;
            if (v.x != 0.0f) s_idx[atomicAdd(&s_cnt, 1)] = base;
            if (v.y != 0.0f) s_idx[atomicAdd(&s_cnt, 1)] = base + 1;
            if (v.z != 0.0f) s_idx[atomicAdd(&s_cnt, 1)] = base + 2;
            if (v.w != 0.0f) s_idx[atomicAdd(&s_cnt, 1)] = base + 3;
        }
        __syncthreads();

        const int cnt = s_cnt;
        // --- gather-accumulate: thread tid owns batch column tid.
        // 4-way unroll -> 4 independent in-flight loads per iteration.
        float a0 = 0.f, a1 = 0.f, a2 = 0.f, a3 = 0.f;
        int i = 0;
        if (use_dd) {
            for (; i + 4 <= cnt; i += 4) {
                a0 += dd[s_idx[i]     * BB + tid];
                a1 += dd[s_idx[i + 1] * BB + tid];
                a2 += dd[s_idx[i + 2] * BB + tid];
                a3 += dd[s_idx[i + 3] * BB + tid];
            }
            for (; i < cnt; ++i) a0 += dd[s_idx[i] * BB + tid];
        } else {
            for (; i + 2 <= cnt; i += 2) {
                int n0 = s_idx[i] * BB + tid;
                int n1 = s_idx[i + 1] * BB + tid;
                a0 += d1[n0] - d2[n0];
                a1 += d1[n1] - d2[n1];
            }
            for (; i < cnt; ++i) {
                int n = s_idx[i] * BB + tid;
                a0 += d1[n] - d2[n];
            }
        }
        float acc = (a0 + a1) + (a2 + a3);

        float w = param[parents[m]] - param[m];
        partial += w * fabsf(acc);
        __syncthreads();   // protect s_cnt/s_idx before next row
    }
    atomicAdd(&w1sum[tid], partial);
}

// ---------------------------------------------------------------------------
// Kernel 3: out = sum_b (ot[b] - 0.5 * w1sum[b])^2   (one block, 256 threads)
// ---------------------------------------------------------------------------
__global__ __launch_bounds__(256) void k_finalize(const float* __restrict__ w1sum,
                                                  const float* __restrict__ ot,
                                                  float* __restrict__ out) {
    __shared__ float s[4];
    int tid = threadIdx.x;
    float e = ot[tid] - 0.5f * w1sum[tid];
    float v = e * e;
    #pragma unroll
    for (int off = 32; off > 0; off >>= 1) v += __shfl_down(v, off, 64);
    if ((tid & 63) == 0) s[tid >> 6] = v;
    __syncthreads();
    if (tid == 0) out[0] = (s[0] + s[1]) + (s[2] + s[3]);
}

// ---------------------------------------------------------------------------
extern "C" void kernel_launch(void* const* d_in, const int* in_sizes, int n_in,
                              void* d_out, int out_size, void* d_ws, size_t ws_size,
                              hipStream_t stream) {
    const float* d1      = (const float*)d_in[0];
    const float* d2      = (const float*)d_in[1];
    const float* ot      = (const float*)d_in[2];
    const float* subtree = (const float*)d_in[3];
    const float* param   = (const float*)d_in[4];
    const int*   parents = (const int*)d_in[5];

    float* ws    = (float*)d_ws;
    float* w1sum = ws;            // 256 floats
    float* dd    = ws + BB;       // NN*BB floats (4 MB) if it fits

    int use_dd = (ws_size >= (size_t)(BB + NN * BB) * sizeof(float)) ? 1 : 0;

    k_diff_zero<<<use_dd ? 1024 : 1, 256, 0, stream>>>(d1, d2, ws, use_dd);
    k_tree_w1<<<2048, 256, 0, stream>>>(subtree, d1, d2, dd, use_dd,
                                        param, parents, w1sum);
    k_finalize<<<1, 256, 0, stream>>>(w1sum, ot, (float*)d_out);
}